// Round 6
// baseline (578.344 us; speedup 1.0000x reference)
//
#include <hip/hip_runtime.h>
#include <hip/hip_bf16.h>

// CustomQuantLinear: out[m][n] = scale[n] * sum_k x[m][k]*(w[n][k]-zp[n]) + bias[n]
// M=8192, N=11008, K=4096.
// R5 -> R6: same int8 pipeline (w exact int8; x per-row quant + exact fp32
// rowsum for the zp term), same 4-slot ring / counted vmcnt(8) / swizzle.
// Schedule change only: hoist all 12 ds_reads + both STAGE issues to group
// top, then ONE barrier -> one lgkm wait -> one 32-MFMA cluster -> vmcnt(8)
// -> one barrier. Halves barrier regions per group (4 -> 2); ledger unchanged.

#define MDIM 8192
#define NDIM 11008
#define KDIM 4096

#define BM 256
#define BN 256
#define BK 64
#define KT (KDIM / BK)   // 64
#define NTM (MDIM / BM)  // 32
#define NTN (NDIM / BN)  // 43
#define NWG (NTM * NTN)  // 1376 = 8*172

typedef signed char i8;
typedef int i32x4 __attribute__((ext_vector_type(4)));

// ---------- prep kernels ----------

// pack w (int32 in [-128,127]) -> int8, 16 elems/thread
__global__ void conv_w8(const int* __restrict__ w, i8* __restrict__ w8) {
    const size_t e = ((size_t)blockIdx.x * 256 + threadIdx.x) << 4;
    const int4 a = *(const int4*)(w + e);
    const int4 b = *(const int4*)(w + e + 4);
    const int4 c = *(const int4*)(w + e + 8);
    const int4 d = *(const int4*)(w + e + 12);
    i8 q[16];
    q[0] = (i8)a.x; q[1] = (i8)a.y; q[2] = (i8)a.z; q[3] = (i8)a.w;
    q[4] = (i8)b.x; q[5] = (i8)b.y; q[6] = (i8)b.z; q[7] = (i8)b.w;
    q[8] = (i8)c.x; q[9] = (i8)c.y; q[10] = (i8)c.z; q[11] = (i8)c.w;
    q[12] = (i8)d.x; q[13] = (i8)d.y; q[14] = (i8)d.z; q[15] = (i8)d.w;
    *(int4*)(w8 + e) = *(const int4*)q;
}

// per-row x quant: xq = rint(x*127/absmax), sx = absmax/127, xs = sum(x) fp32
__global__ __launch_bounds__(256) void conv_xq(const float* __restrict__ x,
                                               i8* __restrict__ xq,
                                               float* __restrict__ sx,
                                               float* __restrict__ xs) {
    __shared__ float ramax[4], rsum[4];
    const int row = blockIdx.x;
    const float* xr = x + (size_t)row * KDIM;
    const int t = threadIdx.x;
    const float4* p = (const float4*)xr + (t << 2);
    float4 v0 = p[0], v1 = p[1], v2 = p[2], v3 = p[3];
    float amax = 0.f, sum = 0.f;
    float vv[16] = {v0.x, v0.y, v0.z, v0.w, v1.x, v1.y, v1.z, v1.w,
                    v2.x, v2.y, v2.z, v2.w, v3.x, v3.y, v3.z, v3.w};
#pragma unroll
    for (int i = 0; i < 16; ++i) {
        amax = fmaxf(amax, fabsf(vv[i]));
        sum += vv[i];
    }
#pragma unroll
    for (int off = 32; off > 0; off >>= 1) {
        amax = fmaxf(amax, __shfl_down(amax, off, 64));
        sum += __shfl_down(sum, off, 64);
    }
    if ((t & 63) == 0) { ramax[t >> 6] = amax; rsum[t >> 6] = sum; }
    __syncthreads();
    amax = fmaxf(fmaxf(ramax[0], ramax[1]), fmaxf(ramax[2], ramax[3]));
    sum = (rsum[0] + rsum[1]) + (rsum[2] + rsum[3]);
    const float inv = (amax > 0.f) ? 127.0f / amax : 0.f;
    if (t == 0) {
        sx[row] = amax * (1.0f / 127.0f);
        xs[row] = sum;
    }
    i8 q[16];
#pragma unroll
    for (int i = 0; i < 16; ++i) q[i] = (i8)(int)rintf(vv[i] * inv);
    *(int4*)(xq + (size_t)row * KDIM + (t << 4)) = *(const int4*)q;
}

// ---------- GEMM ----------

__device__ __forceinline__ void gload16(const i8* g, i8* l) {
    __builtin_amdgcn_global_load_lds(
        (const __attribute__((address_space(1))) unsigned int*)g,
        (__attribute__((address_space(3))) unsigned int*)l, 16, 0, 0);
}

// stage one K-tile operand: [256 rows][64 cols] i8 = 16KB = 512 thr * 2 * 16B
#define STAGE_A(T) do { const int _s = (T) & 3; const int _k = (T) * BK;          \
    gload16(gA0 + _k, &SH[_s][0][wid * 1024]);                                    \
    gload16(gA1 + _k, &SH[_s][0][8192 + wid * 1024]); } while (0)
#define STAGE_B(T) do { const int _s = (T) & 3; const int _k = (T) * BK;          \
    gload16(gB0 + _k, &SH[_s][1][wid * 1024]);                                    \
    gload16(gB1 + _k, &SH[_s][1][8192 + wid * 1024]); } while (0)

// one K-tile group: hoisted 12 ds_read_b128 + 4 gload_lds, then one 32-MFMA
// cluster between a single barrier pair.
#define GROUP(T, DO_STAGE, WAITOP) do {                                           \
    const i8* _sA = &SH[(T) & 3][0][0];                                           \
    const i8* _sB = &SH[(T) & 3][1][0];                                           \
    i32x4 aFr[8], bF[4];                                                          \
    _Pragma("unroll") for (int _f = 0; _f < 8; ++_f)                              \
        aFr[_f] = *(const i32x4*)(_sA + aoff + _f * 1024);                        \
    _Pragma("unroll") for (int _f = 0; _f < 4; ++_f)                              \
        bF[_f] = *(const i32x4*)(_sB + boff + _f * 1024);                         \
    if (DO_STAGE) { STAGE_A((T) + 3); STAGE_B((T) + 3); }                         \
    __builtin_amdgcn_s_barrier();                                                 \
    __builtin_amdgcn_s_setprio(1);                                                \
    _Pragma("unroll") for (int _i = 0; _i < 8; ++_i)                              \
    _Pragma("unroll") for (int _j = 0; _j < 4; ++_j)                              \
        acc[_i][_j] = __builtin_amdgcn_mfma_i32_16x16x64_i8(                      \
            aFr[_i], bF[_j], acc[_i][_j], 0, 0, 0);                               \
    __builtin_amdgcn_s_setprio(0);                                                \
    WAITOP;                                                                       \
    __builtin_amdgcn_s_barrier();                                                 \
} while (0)

__global__ __launch_bounds__(512, 2) void gemm_q(const i8* __restrict__ Xq,
                                                 const i8* __restrict__ Wq,
                                                 const float* __restrict__ sx,
                                                 const float* __restrict__ xs,
                                                 const float* __restrict__ scale,
                                                 const int* __restrict__ zp,
                                                 const float* __restrict__ bias,
                                                 float* __restrict__ out) {
    __shared__ __align__(16) i8 SH[4][2][16384];  // [slot][A|B][256*64] = 128 KiB

    const int tid = threadIdx.x;
    const int wid = tid >> 6;
    const int lane = tid & 63;

    // bijective XCD raster: xcd = bid&7 owns M-tiles 4x..4x+3, n slowest
    const int bid = blockIdx.x;
    const int pm = ((bid & 7) << 2) | ((bid >> 3) & 3);
    const int pn = bid >> 5;
    const int bm0 = pm * BM;
    const int bn0 = pn * BN;

    // staging: thread covers row (tid>>2)(+128), 16 cols at swizzled source col.
    // LDS dest linear (gload_lds); physical[P] = logical[P ^ ((row&8)<<2)].
    const int srow = tid >> 2;
    const int scol = ((tid & 3) << 4) ^ (((tid >> 5) & 1) << 5);
    const i8* gA0 = Xq + (size_t)(bm0 + srow) * KDIM + scol;
    const i8* gA1 = gA0 + (size_t)128 * KDIM;
    const i8* gB0 = Wq + (size_t)(bn0 + srow) * KDIM + scol;
    const i8* gB1 = gB0 + (size_t)128 * KDIM;

    // fragment read offsets (bytes, swizzle applied on read)
    const int wm = wid >> 2, wn = wid & 3;
    const int lr = lane & 15;
    const int kb = (lane >> 4) << 4;            // 0,16,32,48 byte col
    const int swz = (lr & 8) << 2;              // row bit3 -> byte bit5
    const int aoff = (((wm * 128 + lr) << 6) + kb) ^ swz;
    const int boff = (((wn * 64 + lr) << 6) + kb) ^ swz;

    i32x4 acc[8][4];
#pragma unroll
    for (int i = 0; i < 8; ++i)
#pragma unroll
        for (int j = 0; j < 4; ++j) acc[i][j] = (i32x4){0, 0, 0, 0};

    // prologue: stage tiles 0,1,2 (12 loads/wave); tile 0 landed after vmcnt(8)
    STAGE_A(0); STAGE_B(0);
    STAGE_A(1); STAGE_B(1);
    STAGE_A(2); STAGE_B(2);
    asm volatile("s_waitcnt vmcnt(8)" ::: "memory");
    __builtin_amdgcn_s_barrier();

    for (int t = 0; t < KT - 3; ++t) {  // stages tiles 3..63
        GROUP(t, true, asm volatile("s_waitcnt vmcnt(8)" ::: "memory"));
    }
    GROUP(KT - 3, false, asm volatile("s_waitcnt vmcnt(4)" ::: "memory"));
    GROUP(KT - 2, false, asm volatile("s_waitcnt vmcnt(0)" ::: "memory"));
    GROUP(KT - 1, false, (void)0);

    // epilogue: C/D layout col = lane&15, row = (lane>>4)*4 + reg (shape-determined)
    const int rr = (lane >> 4) << 2;
#pragma unroll
    for (int j = 0; j < 4; ++j) {
        const int n = bn0 + wn * 64 + j * 16 + lr;
        const float sc = scale[n];
        const float zpn = (float)zp[n];
        const float bi = bias[n];
#pragma unroll
        for (int i = 0; i < 8; ++i) {
            const int m = bm0 + wm * 128 + i * 16 + rr;
#pragma unroll
            for (int r = 0; r < 4; ++r) {
                const int mm = m + r;
                const float d = (float)acc[i][j][r];
                out[(size_t)mm * NDIM + n] = sc * (sx[mm] * d - zpn * xs[mm]) + bi;
            }
        }
    }
}

// ---------- fallback (ws too small) ----------

__global__ void naive_q(const float* __restrict__ x, const int* __restrict__ wq,
                        const float* __restrict__ scale, const int* __restrict__ zp,
                        const float* __restrict__ bias, float* __restrict__ out) {
    const long long idx = (long long)blockIdx.x * 256 + threadIdx.x;
    if (idx >= (long long)MDIM * NDIM) return;
    const int m = (int)(idx / NDIM);
    const int n = (int)(idx % NDIM);
    const float* xr = x + (long long)m * KDIM;
    const int* wr = wq + (long long)n * KDIM;
    float dot = 0.f, xsum = 0.f;
    for (int k = 0; k < KDIM; ++k) {
        dot += xr[k] * (float)wr[k];
        xsum += xr[k];
    }
    out[idx] = scale[n] * (dot - (float)zp[n] * xsum) + bias[n];
}

extern "C" void kernel_launch(void* const* d_in, const int* in_sizes, int n_in,
                              void* d_out, int out_size, void* d_ws, size_t ws_size,
                              hipStream_t stream) {
    const float* x = (const float*)d_in[0];
    const int* wq = (const int*)d_in[1];
    const float* scale = (const float*)d_in[2];
    const int* zp = (const int*)d_in[3];
    const float* bias = (const float*)d_in[4];
    float* out = (float*)d_out;

    const size_t w8_bytes = (size_t)NDIM * KDIM;      // 45,088,768
    const size_t xq_bytes = (size_t)MDIM * KDIM;      // 33,554,432
    const size_t row_bytes = (size_t)MDIM * 4;        // 32,768
    const size_t need = w8_bytes + xq_bytes + 2 * row_bytes;

    if (ws_size >= need) {
        i8* w8 = (i8*)d_ws;
        i8* xq8 = (i8*)((char*)d_ws + w8_bytes);
        float* sx = (float*)((char*)d_ws + w8_bytes + xq_bytes);
        float* xs = (float*)((char*)d_ws + w8_bytes + xq_bytes + row_bytes);
        conv_w8<<<(unsigned)(w8_bytes / 16 / 256), 256, 0, stream>>>(wq, w8);
        conv_xq<<<MDIM, 256, 0, stream>>>(x, xq8, sx, xs);
        gemm_q<<<NWG, 512, 0, stream>>>(xq8, w8, sx, xs, scale, zp, bias, out);
    } else {
        const long long total = (long long)MDIM * NDIM;
        naive_q<<<(unsigned)((total + 255) / 256), 256, 0, stream>>>(
            x, wq, scale, zp, bias, out);
    }
}

// Round 7
// 545.455 us; speedup vs baseline: 1.0603x; 1.0603x over previous
//
#include <hip/hip_runtime.h>
#include <hip/hip_bf16.h>

// CustomQuantLinear: out[m][n] = scale[n] * sum_k x[m][k]*(w[n][k]-zp[n]) + bias[n]
// M=8192, N=11008, K=4096.
// R6 -> R7: R6's barrier-collapse was neutral-negative -> restore R5's 4-region
// group. New lever: occupancy. BM=256 x BN=128, 8 waves (4Mx2N), 64x64/wave:
// acc 128->64 VGPR, total ~120/wave -> 16 waves/CU; LDS 3-slot ring
// (16KB A + 8KB B = 24KB/slot, 72KB) -> 2 blocks/CU. Counted vmcnt(3),
// 2 tiles ahead. Same XOR-bit5 swizzle (0 conflicts), same int8 numerics.

#define MDIM 8192
#define NDIM 11008
#define KDIM 4096

#define BM 256
#define BN 128
#define BK 64
#define KT (KDIM / BK)   // 64
#define NTM (MDIM / BM)  // 32
#define NTN (NDIM / BN)  // 86
#define NWG (NTM * NTN)  // 2752 = 8*344

#define SLOT 24576       // 16KB A + 8KB B
#define BOFFS 16384      // B region offset within slot

typedef signed char i8;
typedef int i32x4 __attribute__((ext_vector_type(4)));

// ---------- prep kernels ----------

// pack w (int32 in [-128,127]) -> int8, 16 elems/thread
__global__ void conv_w8(const int* __restrict__ w, i8* __restrict__ w8) {
    const size_t e = ((size_t)blockIdx.x * 256 + threadIdx.x) << 4;
    const int4 a = *(const int4*)(w + e);
    const int4 b = *(const int4*)(w + e + 4);
    const int4 c = *(const int4*)(w + e + 8);
    const int4 d = *(const int4*)(w + e + 12);
    i8 q[16];
    q[0] = (i8)a.x; q[1] = (i8)a.y; q[2] = (i8)a.z; q[3] = (i8)a.w;
    q[4] = (i8)b.x; q[5] = (i8)b.y; q[6] = (i8)b.z; q[7] = (i8)b.w;
    q[8] = (i8)c.x; q[9] = (i8)c.y; q[10] = (i8)c.z; q[11] = (i8)c.w;
    q[12] = (i8)d.x; q[13] = (i8)d.y; q[14] = (i8)d.z; q[15] = (i8)d.w;
    *(int4*)(w8 + e) = *(const int4*)q;
}

// per-row x quant: xq = rint(x*127/absmax), sx = absmax/127, xs = sum(x) fp32
__global__ __launch_bounds__(256) void conv_xq(const float* __restrict__ x,
                                               i8* __restrict__ xq,
                                               float* __restrict__ sx,
                                               float* __restrict__ xs) {
    __shared__ float ramax[4], rsum[4];
    const int row = blockIdx.x;
    const float* xr = x + (size_t)row * KDIM;
    const int t = threadIdx.x;
    const float4* p = (const float4*)xr + (t << 2);
    float4 v0 = p[0], v1 = p[1], v2 = p[2], v3 = p[3];
    float amax = 0.f, sum = 0.f;
    float vv[16] = {v0.x, v0.y, v0.z, v0.w, v1.x, v1.y, v1.z, v1.w,
                    v2.x, v2.y, v2.z, v2.w, v3.x, v3.y, v3.z, v3.w};
#pragma unroll
    for (int i = 0; i < 16; ++i) {
        amax = fmaxf(amax, fabsf(vv[i]));
        sum += vv[i];
    }
#pragma unroll
    for (int off = 32; off > 0; off >>= 1) {
        amax = fmaxf(amax, __shfl_down(amax, off, 64));
        sum += __shfl_down(sum, off, 64);
    }
    if ((t & 63) == 0) { ramax[t >> 6] = amax; rsum[t >> 6] = sum; }
    __syncthreads();
    amax = fmaxf(fmaxf(ramax[0], ramax[1]), fmaxf(ramax[2], ramax[3]));
    sum = (rsum[0] + rsum[1]) + (rsum[2] + rsum[3]);
    const float inv = (amax > 0.f) ? 127.0f / amax : 0.f;
    if (t == 0) {
        sx[row] = amax * (1.0f / 127.0f);
        xs[row] = sum;
    }
    i8 q[16];
#pragma unroll
    for (int i = 0; i < 16; ++i) q[i] = (i8)(int)rintf(vv[i] * inv);
    *(int4*)(xq + (size_t)row * KDIM + (t << 4)) = *(const int4*)q;
}

// ---------- GEMM ----------

__device__ __forceinline__ void gload16(const i8* g, i8* l) {
    __builtin_amdgcn_global_load_lds(
        (const __attribute__((address_space(1))) unsigned int*)g,
        (__attribute__((address_space(3))) unsigned int*)l, 16, 0, 0);
}

// A tile [256][64] = 16KB = 2 loads/thread; B tile [128][64] = 8KB = 1 load.
#define STAGE_A(T) do { const int _s = (T) % 3; const int _k = (T) * BK;          \
    gload16(gA0 + _k, &SH[_s][wid * 1024]);                                       \
    gload16(gA1 + _k, &SH[_s][8192 + wid * 1024]); } while (0)
#define STAGE_B(T) do { const int _s = (T) % 3; const int _k = (T) * BK;          \
    gload16(gB0 + _k, &SH[_s][BOFFS + wid * 1024]); } while (0)

// one K-tile group, R5's 4-region structure: 2 phases of 8 MFMA each.
#define GROUP(T, DO_STAGE, WAITOP) do {                                           \
    const i8* _sA = &SH[(T) % 3][0];                                              \
    const i8* _sB = &SH[(T) % 3][BOFFS];                                          \
    i32x4 aF[2], bF[4], aG[2];                                                    \
    _Pragma("unroll") for (int _f = 0; _f < 2; ++_f)                              \
        aF[_f] = *(const i32x4*)(_sA + aoff + _f * 1024);                         \
    _Pragma("unroll") for (int _f = 0; _f < 4; ++_f)                              \
        bF[_f] = *(const i32x4*)(_sB + boff + _f * 1024);                         \
    if (DO_STAGE) STAGE_A((T) + 2);                                               \
    __builtin_amdgcn_s_barrier();                                                 \
    __builtin_amdgcn_s_setprio(1);                                                \
    _Pragma("unroll") for (int _i = 0; _i < 2; ++_i)                              \
    _Pragma("unroll") for (int _j = 0; _j < 4; ++_j)                              \
        acc[_i][_j] = __builtin_amdgcn_mfma_i32_16x16x64_i8(                      \
            aF[_i], bF[_j], acc[_i][_j], 0, 0, 0);                                \
    __builtin_amdgcn_s_setprio(0);                                                \
    __builtin_amdgcn_s_barrier();                                                 \
    _Pragma("unroll") for (int _f = 0; _f < 2; ++_f)                              \
        aG[_f] = *(const i32x4*)(_sA + aoff + (_f + 2) * 1024);                   \
    if (DO_STAGE) STAGE_B((T) + 2);                                               \
    __builtin_amdgcn_s_barrier();                                                 \
    __builtin_amdgcn_s_setprio(1);                                                \
    _Pragma("unroll") for (int _i = 0; _i < 2; ++_i)                              \
    _Pragma("unroll") for (int _j = 0; _j < 4; ++_j)                              \
        acc[_i + 2][_j] = __builtin_amdgcn_mfma_i32_16x16x64_i8(                  \
            aG[_i], bF[_j], acc[_i + 2][_j], 0, 0, 0);                            \
    __builtin_amdgcn_s_setprio(0);                                                \
    WAITOP;                                                                       \
    __builtin_amdgcn_s_barrier();                                                 \
} while (0)

__global__ __launch_bounds__(512, 4) void gemm_q(const i8* __restrict__ Xq,
                                                 const i8* __restrict__ Wq,
                                                 const float* __restrict__ sx,
                                                 const float* __restrict__ xs,
                                                 const float* __restrict__ scale,
                                                 const int* __restrict__ zp,
                                                 const float* __restrict__ bias,
                                                 float* __restrict__ out) {
    __shared__ __align__(16) i8 SH[3][SLOT];  // 72 KiB -> 2 blocks/CU

    const int tid = threadIdx.x;
    const int wid = tid >> 6;
    const int lane = tid & 63;

    // bijective XCD raster: xcd owns pm in [4*xcd, 4*xcd+4), pm-fastest in 4
    const int bid = blockIdx.x;
    const int off = bid >> 3;                       // 0..343
    const int pm = ((bid & 7) << 2) | (off & 3);    // 0..31
    const int pn = off >> 2;                        // 0..85
    const int bm0 = pm * BM;
    const int bn0 = pn * BN;

    // staging source (R5 formulas): row = tid>>2, col pre-swizzled so that
    // physical[P] = logical[P ^ ((row&8)<<2)] with linear gload_lds dest.
    const int srow = tid >> 2;
    const int scol = ((tid & 3) << 4) ^ (((tid >> 5) & 1) << 5);
    const i8* gA0 = Xq + (size_t)(bm0 + srow) * KDIM + scol;
    const i8* gA1 = gA0 + (size_t)128 * KDIM;
    const i8* gB0 = Wq + (size_t)(bn0 + srow) * KDIM + scol;

    // wave map: 4M x 2N, per-wave output 64x64
    const int wm = wid >> 1, wn = wid & 1;
    const int lr = lane & 15;
    const int kb = (lane >> 4) << 4;            // 0,16,32,48 byte col
    const int swz = (lr & 8) << 2;              // row bit3 -> byte bit5
    const int aoff = (((wm * 64 + lr) << 6) + kb) ^ swz;
    const int boff = (((wn * 64 + lr) << 6) + kb) ^ swz;

    i32x4 acc[4][4];
#pragma unroll
    for (int i = 0; i < 4; ++i)
#pragma unroll
        for (int j = 0; j < 4; ++j) acc[i][j] = (i32x4){0, 0, 0, 0};

    // prologue: stage tiles 0,1 (6 loads/thread-group); tile 0 landed at vmcnt(3)
    STAGE_A(0); STAGE_B(0);
    STAGE_A(1); STAGE_B(1);
    asm volatile("s_waitcnt vmcnt(3)" ::: "memory");
    __builtin_amdgcn_s_barrier();

    for (int t = 0; t < KT - 2; ++t) {  // stages tiles 2..63
        GROUP(t, true, asm volatile("s_waitcnt vmcnt(3)" ::: "memory"));
    }
    GROUP(KT - 2, false, asm volatile("s_waitcnt vmcnt(0)" ::: "memory"));
    GROUP(KT - 1, false, (void)0);

    // epilogue: C/D layout col = lane&15, row = (lane>>4)*4 + reg
    const int rr = (lane >> 4) << 2;
#pragma unroll
    for (int j = 0; j < 4; ++j) {
        const int n = bn0 + wn * 64 + j * 16 + lr;
        const float sc = scale[n];
        const float zpn = (float)zp[n];
        const float bi = bias[n];
#pragma unroll
        for (int i = 0; i < 4; ++i) {
            const int m = bm0 + wm * 64 + i * 16 + rr;
#pragma unroll
            for (int r = 0; r < 4; ++r) {
                const int mm = m + r;
                const float d = (float)acc[i][j][r];
                out[(size_t)mm * NDIM + n] = sc * (sx[mm] * d - zpn * xs[mm]) + bi;
            }
        }
    }
}

// ---------- fallback (ws too small) ----------

__global__ void naive_q(const float* __restrict__ x, const int* __restrict__ wq,
                        const float* __restrict__ scale, const int* __restrict__ zp,
                        const float* __restrict__ bias, float* __restrict__ out) {
    const long long idx = (long long)blockIdx.x * 256 + threadIdx.x;
    if (idx >= (long long)MDIM * NDIM) return;
    const int m = (int)(idx / NDIM);
    const int n = (int)(idx % NDIM);
    const float* xr = x + (long long)m * KDIM;
    const int* wr = wq + (long long)n * KDIM;
    float dot = 0.f, xsum = 0.f;
    for (int k = 0; k < KDIM; ++k) {
        dot += xr[k] * (float)wr[k];
        xsum += xr[k];
    }
    out[idx] = scale[n] * (dot - (float)zp[n] * xsum) + bias[n];
}

extern "C" void kernel_launch(void* const* d_in, const int* in_sizes, int n_in,
                              void* d_out, int out_size, void* d_ws, size_t ws_size,
                              hipStream_t stream) {
    const float* x = (const float*)d_in[0];
    const int* wq = (const int*)d_in[1];
    const float* scale = (const float*)d_in[2];
    const int* zp = (const int*)d_in[3];
    const float* bias = (const float*)d_in[4];
    float* out = (float*)d_out;

    const size_t w8_bytes = (size_t)NDIM * KDIM;      // 45,088,768
    const size_t xq_bytes = (size_t)MDIM * KDIM;      // 33,554,432
    const size_t row_bytes = (size_t)MDIM * 4;        // 32,768
    const size_t need = w8_bytes + xq_bytes + 2 * row_bytes;

    if (ws_size >= need) {
        i8* w8 = (i8*)d_ws;
        i8* xq8 = (i8*)((char*)d_ws + w8_bytes);
        float* sx = (float*)((char*)d_ws + w8_bytes + xq_bytes);
        float* xs = (float*)((char*)d_ws + w8_bytes + xq_bytes + row_bytes);
        conv_w8<<<(unsigned)(w8_bytes / 16 / 256), 256, 0, stream>>>(wq, w8);
        conv_xq<<<MDIM, 256, 0, stream>>>(x, xq8, sx, xs);
        gemm_q<<<NWG, 512, 0, stream>>>(xq8, w8, sx, xs, scale, zp, bias, out);
    } else {
        const long long total = (long long)MDIM * NDIM;
        naive_q<<<(unsigned)((total + 255) / 256), 256, 0, stream>>>(
            x, wq, scale, zp, bias, out);
    }
}